// Round 9
// baseline (408.793 us; speedup 1.0000x reference)
//
#include <hip/hip_runtime.h>
#include <hip/hip_bf16.h>
#include <stdint.h>

// XCA (cross-covariance attention), B=8 N=8192 C=384 H=8 Dh=48.
// R12: R11 A/B showed staging path is irrelevant (gload 131.7 vs reg 133.0);
// the 2-barrier-per-k-step structure exposes full load latency every step
// (1480 cyc/step vs 260 cyc MFMA; MfmaUtil 17.5% == compute floor / duration).
// Fix: T3-minimum 2-phase pipeline (guide m230-V0): LDS double-buffer,
// per step { STAGE(buf[nxt], s+1) ; ds_read+MFMA on buf[cur] ; __syncthreads }
// -> ONE barrier/step, stage latency overlaps compute. __syncthreads drains
// vmcnt so the staged half is ready+published at each barrier (no inline asm).
// Applied to k_gemm_qkv (108 steps, continuous s across jt) and k_gemm_out
// (36 steps). Everything else identical to R11 (407us).

typedef __bf16 bf16_t;
typedef __attribute__((ext_vector_type(8))) __bf16 bf16x8;
typedef __attribute__((ext_vector_type(4))) __bf16 bf16x4;
typedef __attribute__((ext_vector_type(4))) float f32x4;

#define NTOK 8192
#define CDIM 384
#define WH   25165824   // 8*8*48*8192 elements per q/k plane
#define DHN  393216     // 48*8192

#define XCHUNKS 3145728   // 25,165,824 X elems / 8
#define TCHUNKS 3201024   // + 442,368 W elems / 8

__device__ __forceinline__ f32x4 mfma16(bf16x8 a, bf16x8 b, f32x4 c) {
  return __builtin_amdgcn_mfma_f32_16x16x32_bf16(a, b, c, 0, 0, 0);
}

// async global->LDS, 16B per lane (wave-uniform base + lane*16 idiom).
__device__ __forceinline__ void gload16(bf16_t* lds, const bf16_t* g) {
  __builtin_amdgcn_global_load_lds(
      (const __attribute__((address_space(1))) void*)g,
      (__attribute__((address_space(3))) void*)lds, 16, 0, 0);
}

template <bool BF16>
__device__ __forceinline__ bf16x8 load8(const void* p, int idx) {
  if constexpr (BF16) {
    return *(const bf16x8*)((const bf16_t*)p + idx);
  } else {
    const float* f = (const float*)p + idx;
    f32x4 a = *(const f32x4*)f;
    f32x4 b = *(const f32x4*)(f + 4);
    bf16x8 r;
    r[0] = (bf16_t)a[0]; r[1] = (bf16_t)a[1]; r[2] = (bf16_t)a[2]; r[3] = (bf16_t)a[3];
    r[4] = (bf16_t)b[0]; r[5] = (bf16_t)b[1]; r[6] = (bf16_t)b[2]; r[7] = (bf16_t)b[3];
    return r;
  }
}

// ---------------- probe: are inputs bf16 (1) or f32 (0)? ----------------
__global__ void k_probe(const uint32_t* __restrict__ X, int* __restrict__ flag) {
  __shared__ int cnt;
  if (threadIdx.x == 0) cnt = 0;
  __syncthreads();
  const uint32_t w = X[threadIdx.x];
  const int e = (int)((w >> 7) & 0xFF);  // exponent of low-16 as bf16
  const int sane = (e >= 110 && e <= 131) ? 1 : 0;
  atomicAdd(&cnt, sane);
  __syncthreads();
  if (threadIdx.x == 0) *flag = (cnt >= 128) ? 1 : 0;
}

// ---------------- zero fp32 accumulators ----------------
__global__ void k_zero(float* __restrict__ p, int n) {
  int i = blockIdx.x * 256 + threadIdx.x;
  if (i < n) p[i] = 0.f;
}

// ---------------- cvt: X,Wqkv (f32 or bf16) -> bf16 workspace ----------------
__global__ void k_cvt(const void* __restrict__ X, const void* __restrict__ Wqkv,
                      bf16_t* __restrict__ Xb, bf16_t* __restrict__ Wb,
                      const int* __restrict__ flagp) {
  const int isb = *flagp;
  const int G = gridDim.x * 256;
  for (int c = blockIdx.x * 256 + threadIdx.x; c < TCHUNKS; c += G) {
    const bool isX = c < XCHUNKS;
    const int lc = isX ? c : c - XCHUNKS;          // chunk within its buffer
    const void* src = isX ? X : Wqkv;
    bf16_t* dst = (isX ? Xb : Wb) + (size_t)lc * 8;
    if (isb) {
      *(bf16x8*)dst = *((const bf16x8*)src + lc);
    } else {
      const f32x4 a = *((const f32x4*)src + lc * 2);
      const f32x4 b = *((const f32x4*)src + lc * 2 + 1);
      bf16x8 r;
      r[0] = (bf16_t)a[0]; r[1] = (bf16_t)a[1]; r[2] = (bf16_t)a[2]; r[3] = (bf16_t)a[3];
      r[4] = (bf16_t)b[0]; r[5] = (bf16_t)b[1]; r[6] = (bf16_t)b[2]; r[7] = (bf16_t)b[3];
      *(bf16x8*)dst = r;
    }
  }
}

// ---------------- K1: qkv = x @ w_qkv^T (pipelined main path) ----------------
// Grid (512). jt=0..8 inside; 2 blocks/CU; LDS dbuf 2x(8KB A + 8KB B);
// one __syncthreads per k-step; stage for step s+1 issued before compute of s.
// q/k tiles (which<2): swapped MFMA (D row = token) -> bf16x4 stores along N.
// v tiles: original order (D row = channel) -> bf16x4 stores along C.
__device__ __forceinline__ void qkv_body_pipe(const bf16_t* __restrict__ XB,
                                              const bf16_t* __restrict__ WB,
                                              bf16_t* __restrict__ qkv,
                                              bf16_t* As, bf16_t* Bs) {
  const int tid = threadIdx.x;
  const int lane = tid & 63;
  const int wr = tid >> 7, wc = (tid >> 6) & 1;
  const int q4 = lane >> 4, l16 = lane & 15;
  const int rowB0 = blockIdx.x * 128;
  const int r0 = tid >> 2, kk = (tid & 3) << 3;
  const int bb = rowB0 >> 13;       // batch index (tiles never cross b)
  const int nB = rowB0 & 8191;      // token base within batch

  // stage k-step (jts, ks) into LDS half nxt
  auto STAGE = [&](int jts, int ks, int nxt) {
    const int rowA0 = jts * 128;
    const int k0 = ks * 32;
    bf16_t* Ad = As + nxt * 4096;
    bf16_t* Bd = Bs + nxt * 4096;
    gload16(Ad + tid * 8,         WB + (rowA0 + r0) * CDIM + k0 + kk);
    gload16(Ad + (tid + 256) * 8, WB + (rowA0 + r0 + 64) * CDIM + k0 + kk);
    gload16(Bd + tid * 8,         XB + (rowB0 + r0) * CDIM + k0 + kk);
    gload16(Bd + (tid + 256) * 8, XB + (rowB0 + r0 + 64) * CDIM + k0 + kk);
  };

  STAGE(0, 0, 0);
  __syncthreads();   // drain: buf0 staged + visible
  int cur = 0;

  for (int jt = 0; jt < 9; jt++) {
    const int which = jt / 3;       // 0=q 1=k 2=v (uniform per jt)
    const int jtt = jt - which * 3;
    f32x4 acc[4][4];
#pragma unroll
    for (int i = 0; i < 4; i++)
#pragma unroll
      for (int j = 0; j < 4; j++) acc[i][j] = (f32x4){0.f, 0.f, 0.f, 0.f};

    for (int k = 0; k < 12; k++) {
      // issue next step's stage into the other half (uniform guard)
      if (!(jt == 8 && k == 11)) {
        int kn = k + 1, jn = jt;
        if (kn == 12) { kn = 0; jn = jt + 1; }
        STAGE(jn, kn, cur ^ 1);
      }
      const bf16_t* Ac = As + cur * 4096;
      const bf16_t* Bc = Bs + cur * 4096;
      bf16x8 af[4], bfr[4];
#pragma unroll
      for (int i = 0; i < 4; i++) {
        af[i]  = *(const bf16x8*)&Ac[(wr * 64 + i * 16 + l16) * 32 + q4 * 8];
        bfr[i] = *(const bf16x8*)&Bc[(wc * 64 + i * 16 + l16) * 32 + q4 * 8];
      }
      if (which < 2) {
#pragma unroll
        for (int i = 0; i < 4; i++)
#pragma unroll
          for (int j = 0; j < 4; j++) acc[i][j] = mfma16(bfr[j], af[i], acc[i][j]);
      } else {
#pragma unroll
        for (int i = 0; i < 4; i++)
#pragma unroll
          for (int j = 0; j < 4; j++) acc[i][j] = mfma16(af[i], bfr[j], acc[i][j]);
      }
      __syncthreads();  // drains stage vmcnt + publishes; guards next overwrite
      cur ^= 1;
    }

    if (which < 2) {
      // swapped: acc[i][j][r] = D[token = rowB0+wc*64+j*16+q4*4+r][ch = rowA0+wr*64+i*16+l16]
#pragma unroll
      for (int i = 0; i < 4; i++) {
        const int rin = jtt * 128 + wr * 64 + i * 16 + l16;  // channel within plane
        const int h = rin / 48, dh = rin - h * 48;
        bf16_t* rowp = qkv + which * WH + (bb * 8 + h) * DHN + dh * NTOK
                       + nB + wc * 64 + q4 * 4;
#pragma unroll
        for (int j = 0; j < 4; j++) {
          bf16x4 o = {(bf16_t)acc[i][j][0], (bf16_t)acc[i][j][1],
                      (bf16_t)acc[i][j][2], (bf16_t)acc[i][j][3]};
          *(bf16x4*)(rowp + j * 16) = o;
        }
      }
    } else {
      // original: acc[i][j][r] = D[ch = rowA0+wr*64+i*16+q4*4+r][token = rowB0+wc*64+j*16+l16]
#pragma unroll
      for (int i = 0; i < 4; i++) {
        const int rin0 = jtt * 128 + wr * 64 + i * 16 + q4 * 4;  // c within v
#pragma unroll
        for (int j = 0; j < 4; j++) {
          const int mg = rowB0 + wc * 64 + j * 16 + l16;
          bf16x4 o = {(bf16_t)acc[i][j][0], (bf16_t)acc[i][j][1],
                      (bf16_t)acc[i][j][2], (bf16_t)acc[i][j][3]};
          *(bf16x4*)(qkv + 2 * WH + mg * CDIM + rin0) = o;
        }
      }
    }
  }
}

__global__ __launch_bounds__(256, 2) void k_gemm_qkv(
    const bf16_t* __restrict__ Xb, const bf16_t* __restrict__ Wb,
    bf16_t* __restrict__ qkv) {
  __shared__ __align__(16) bf16_t As[2 * 4096];
  __shared__ __align__(16) bf16_t Bs[2 * 4096];
  qkv_body_pipe(Xb, Wb, qkv, As, Bs);
}

// ---------------- fallback path (ws too small): legacy 2-barrier reg-staging --
template <bool BF16>
__device__ __forceinline__ void qkv_body_legacy(const void* __restrict__ X,
                                                const void* __restrict__ Wqkv,
                                                bf16_t* __restrict__ qkv,
                                                bf16_t* As, bf16_t* Bs) {
  const int tid = threadIdx.x;
  const int lane = tid & 63;
  const int wr = tid >> 7, wc = (tid >> 6) & 1;
  const int q4 = lane >> 4, l16 = lane & 15;
  const int rowB0 = blockIdx.x * 128;
  const int r0 = tid >> 2, kk = (tid & 3) << 3;
  const int bb = rowB0 >> 13;
  const int nB = rowB0 & 8191;

  for (int jt = 0; jt < 9; jt++) {
    const int rowA0 = jt * 128;
    const int which = jt / 3;
    const int jtt = jt - which * 3;
    f32x4 acc[4][4];
#pragma unroll
    for (int i = 0; i < 4; i++)
#pragma unroll
      for (int j = 0; j < 4; j++) acc[i][j] = (f32x4){0.f, 0.f, 0.f, 0.f};

    for (int k0 = 0; k0 < CDIM; k0 += 32) {
      bf16x8 a0 = load8<BF16>(Wqkv, (rowA0 + r0) * CDIM + k0 + kk);
      bf16x8 a1 = load8<BF16>(Wqkv, (rowA0 + r0 + 64) * CDIM + k0 + kk);
      bf16x8 b0 = load8<BF16>(X, (rowB0 + r0) * CDIM + k0 + kk);
      bf16x8 b1 = load8<BF16>(X, (rowB0 + r0 + 64) * CDIM + k0 + kk);
      __syncthreads();
      *(bf16x8*)&As[tid * 8] = a0;
      *(bf16x8*)&As[(tid + 256) * 8] = a1;
      *(bf16x8*)&Bs[tid * 8] = b0;
      *(bf16x8*)&Bs[(tid + 256) * 8] = b1;
      __syncthreads();
      bf16x8 af[4], bfr[4];
#pragma unroll
      for (int i = 0; i < 4; i++) {
        af[i]  = *(const bf16x8*)&As[(wr * 64 + i * 16 + l16) * 32 + q4 * 8];
        bfr[i] = *(const bf16x8*)&Bs[(wc * 64 + i * 16 + l16) * 32 + q4 * 8];
      }
      if (which < 2) {
#pragma unroll
        for (int i = 0; i < 4; i++)
#pragma unroll
          for (int j = 0; j < 4; j++) acc[i][j] = mfma16(bfr[j], af[i], acc[i][j]);
      } else {
#pragma unroll
        for (int i = 0; i < 4; i++)
#pragma unroll
          for (int j = 0; j < 4; j++) acc[i][j] = mfma16(af[i], bfr[j], acc[i][j]);
      }
    }

    if (which < 2) {
#pragma unroll
      for (int i = 0; i < 4; i++) {
        const int rin = jtt * 128 + wr * 64 + i * 16 + l16;
        const int h = rin / 48, dh = rin - h * 48;
        bf16_t* rowp = qkv + which * WH + (bb * 8 + h) * DHN + dh * NTOK
                       + nB + wc * 64 + q4 * 4;
#pragma unroll
        for (int j = 0; j < 4; j++) {
          bf16x4 o = {(bf16_t)acc[i][j][0], (bf16_t)acc[i][j][1],
                      (bf16_t)acc[i][j][2], (bf16_t)acc[i][j][3]};
          *(bf16x4*)(rowp + j * 16) = o;
        }
      }
    } else {
#pragma unroll
      for (int i = 0; i < 4; i++) {
        const int rin0 = jtt * 128 + wr * 64 + i * 16 + q4 * 4;
#pragma unroll
        for (int j = 0; j < 4; j++) {
          const int mg = rowB0 + wc * 64 + j * 16 + l16;
          bf16x4 o = {(bf16_t)acc[i][j][0], (bf16_t)acc[i][j][1],
                      (bf16_t)acc[i][j][2], (bf16_t)acc[i][j][3]};
          *(bf16x4*)(qkv + 2 * WH + mg * CDIM + rin0) = o;
        }
      }
    }
  }
}

__global__ __launch_bounds__(256, 2) void k_gemm_qkv_bf16(
    const void* __restrict__ X, const void* __restrict__ Wqkv,
    bf16_t* __restrict__ qkv, const int* __restrict__ flagp) {
  __shared__ __align__(16) bf16_t As[128 * 32];
  __shared__ __align__(16) bf16_t Bs[128 * 32];
  if (!*flagp) return;
  qkv_body_legacy<true>(X, Wqkv, qkv, As, Bs);
}

__global__ __launch_bounds__(256, 2) void k_gemm_qkv_f32(
    const void* __restrict__ X, const void* __restrict__ Wqkv,
    bf16_t* __restrict__ qkv, const int* __restrict__ flagp) {
  __shared__ __align__(16) bf16_t As[128 * 32];
  __shared__ __align__(16) bf16_t Bs[128 * 32];
  if (*flagp) return;
  qkv_body_legacy<false>(X, Wqkv, qkv, As, Bs);
}

// ---------------- K2: Gram S=Q K^T + sumsq ----------------
__global__ __launch_bounds__(256, 2) void k_gram(
    const bf16_t* __restrict__ qkv, float* __restrict__ S_acc, float* __restrict__ ssq_acc) {
  __shared__ __align__(16) float sm[9312];  // 37,248 B
  bf16_t* Qs = (bf16_t*)sm;                 // 6144 bf16 = [4][48][32]
  bf16_t* Ks = Qs + 6144;
  float* ssq_sm = sm + 9216;                // 96 floats

  const int tid = threadIdx.x;
  const int wave = tid >> 6, lane = tid & 63, q4 = lane >> 4, l16 = lane & 15;
  const int s = blockIdx.x, bh = blockIdx.y;
  const bf16_t* Qg = qkv + bh * DHN;
  const bf16_t* Kg = qkv + WH + bh * DHN;

  if (tid < 96) ssq_sm[tid] = 0.f;

  f32x4 acc[3][3];
#pragma unroll
  for (int i = 0; i < 3; i++)
#pragma unroll
    for (int j = 0; j < 3; j++) acc[i][j] = (f32x4){0.f, 0.f, 0.f, 0.f};
  float qss[3] = {0.f, 0.f, 0.f}, kss[3] = {0.f, 0.f, 0.f};

  for (int t0 = 0; t0 < 8; t0++) {
    const int n0 = s * 1024 + t0 * 128;
    bf16x8 qv[3], kv[3];
#pragma unroll
    for (int jj = 0; jj < 3; jj++) {
      const int c = jj * 256 + tid;
      const int st = c / 192, rem = c - st * 192;
      const int row = rem >> 2, kk = (rem & 3) << 3;
      const int gofs = row * NTOK + n0 + st * 32 + kk;
      qv[jj] = *(const bf16x8*)(Qg + gofs);
      kv[jj] = *(const bf16x8*)(Kg + gofs);
    }
    __syncthreads();
#pragma unroll
    for (int jj = 0; jj < 3; jj++) {
      *(bf16x8*)&Qs[(jj * 256 + tid) * 8] = qv[jj];
      *(bf16x8*)&Ks[(jj * 256 + tid) * 8] = kv[jj];
    }
    __syncthreads();
    bf16x8 qf[3], kf[3];
#pragma unroll
    for (int i = 0; i < 3; i++) {
      qf[i] = *(const bf16x8*)&Qs[wave * 1536 + (i * 16 + l16) * 32 + q4 * 8];
      kf[i] = *(const bf16x8*)&Ks[wave * 1536 + (i * 16 + l16) * 32 + q4 * 8];
    }
#pragma unroll
    for (int i = 0; i < 3; i++) {
#pragma unroll
      for (int u = 0; u < 8; u++) {
        const float qv2 = (float)qf[i][u], kv2 = (float)kf[i][u];
        qss[i] += qv2 * qv2;
        kss[i] += kv2 * kv2;
      }
#pragma unroll
      for (int j = 0; j < 3; j++) acc[i][j] = mfma16(qf[i], kf[j], acc[i][j]);
    }
  }

  __syncthreads();
  float* red = sm;  // 4 waves x 2304 fp32
#pragma unroll
  for (int i = 0; i < 3; i++)
#pragma unroll
    for (int j = 0; j < 3; j++)
#pragma unroll
      for (int r = 0; r < 4; r++)
        red[wave * 2304 + (i * 3 + j) * 256 + lane * 4 + r] = acc[i][j][r];
#pragma unroll
  for (int i = 0; i < 3; i++) {
    atomicAdd(&ssq_sm[i * 16 + l16], qss[i]);
    atomicAdd(&ssq_sm[48 + i * 16 + l16], kss[i]);
  }
  __syncthreads();
  for (int idx = tid; idx < 2304; idx += 256) {
    const float v = red[idx] + red[2304 + idx] + red[4608 + idx] + red[6912 + idx];
    const int tile = idx >> 8, ln = (idx >> 2) & 63, r = idx & 3;
    const int i = tile / 3, j = tile - i * 3;
    const int d = i * 16 + ((ln >> 4) << 2) + r;
    const int e = j * 16 + (ln & 15);
    atomicAdd(&S_acc[bh * 2304 + d * 48 + e], v);
  }
  if (tid < 96) atomicAdd(&ssq_acc[bh * 96 + tid], ssq_sm[tid]);
}

// ---------------- K3: softmax(S / (|q_d||k_e|)) ----------------
__global__ void k_softmax(const float* __restrict__ S_acc, const float* __restrict__ ssq_acc,
                          float* __restrict__ attn_f) {
  __shared__ float invk_sm[48];
  const int bh = blockIdx.x, d = threadIdx.x;
  if (d < 48) invk_sm[d] = 1.f / fmaxf(sqrtf(ssq_acc[bh * 96 + 48 + d]), 1e-12f);
  __syncthreads();
  if (d < 48) {
    const float invq = 1.f / fmaxf(sqrtf(ssq_acc[bh * 96 + d]), 1e-12f);
    float lg[48], mx = -1e30f;
#pragma unroll
    for (int e = 0; e < 48; e++) {
      lg[e] = S_acc[bh * 2304 + d * 48 + e] * invq * invk_sm[e];
      mx = fmaxf(mx, lg[e]);
    }
    float ssum = 0.f;
#pragma unroll
    for (int e = 0; e < 48; e++) { lg[e] = expf(lg[e] - mx); ssum += lg[e]; }
    const float inv = 1.f / ssum;
#pragma unroll
    for (int e = 0; e < 48; e++) attn_f[bh * 2304 + d * 48 + e] = lg[e] * inv;
  }
}

// ---------------- K4: Weff_b[c'][h*48+e] = sum_d Wp[c'][h*48+d] attn[bh][d][e] ------
// Register-tiny LDS-tile formulation (R10, 162us -> ~10us).
__global__ void k_weff(
    const float* __restrict__ attn_f, const void* __restrict__ Wp,
    bf16_t* __restrict__ Weff, const int* __restrict__ flagp) {
  __shared__ float a_sm[2304];  // attn[d][e]
  __shared__ float w_sm[2304];  // Wp[c'_local][d]
  const int isb = *flagp;
  const int bid = blockIdx.x;
  const int ct = bid & 7, h = (bid >> 3) & 7, b = bid >> 6;
  const int bh = b * 8 + h;
  const int tid = threadIdx.x;

  for (int i = tid; i < 2304; i += 256) {
    a_sm[i] = attn_f[bh * 2304 + i];
    const int r = i / 48, c = i - r * 48;
    const int gi = (ct * 48 + r) * CDIM + h * 48 + c;
    w_sm[i] = isb ? (float)((const bf16_t*)Wp)[gi] : ((const float*)Wp)[gi];
  }
  __syncthreads();

  for (int o = tid; o < 2304; o += 256) {
    const int r = o / 48, e = o - r * 48;
    float s = 0.f;
#pragma unroll 8
    for (int d = 0; d < 48; d++) s += w_sm[r * 48 + d] * a_sm[d * 48 + e];
    Weff[b * 147456 + (ct * 48 + r) * CDIM + h * 48 + e] = (bf16_t)s;
  }
}

// ---------------- K5: out[b,n,c'] = sum_c Weff_b[c'][c] V[b,n,c] + bias[c'] --------
// Grid (64 nt, 8 b); ct=0..2 inside; 2 blocks/CU; pipelined dbuf (36 steps).
__global__ __launch_bounds__(256, 2) void k_gemm_out(
    const bf16_t* __restrict__ Weff, const bf16_t* __restrict__ qkv,
    const void* __restrict__ bias, void* __restrict__ out, const int* __restrict__ flagp) {
  __shared__ __align__(16) bf16_t As[2 * 4096];
  __shared__ __align__(16) bf16_t Bs[2 * 4096];
  const int isb = *flagp;
  const int tid = threadIdx.x;
  const int lane = tid & 63;
  const int wr = tid >> 7, wc = (tid >> 6) & 1;
  const int q4 = lane >> 4, l16 = lane & 15;
  const int b = blockIdx.y;
  const int rowB0 = blockIdx.x * 128;  // n tile
  const bf16_t* Aa = Weff + b * 147456;
  const bf16_t* Ba = qkv + 2 * WH + b * (NTOK * CDIM);
  const int r0 = tid >> 2, kk = (tid & 3) << 3;

  auto STAGE = [&](int cts, int ks, int nxt) {
    const int rowA0 = cts * 128;
    const int k0 = ks * 32;
    bf16_t* Ad = As + nxt * 4096;
    bf16_t* Bd = Bs + nxt * 4096;
    gload16(Ad + tid * 8,         Aa + (rowA0 + r0) * CDIM + k0 + kk);
    gload16(Ad + (tid + 256) * 8, Aa + (rowA0 + r0 + 64) * CDIM + k0 + kk);
    gload16(Bd + tid * 8,         Ba + (rowB0 + r0) * CDIM + k0 + kk);
    gload16(Bd + (tid + 256) * 8, Ba + (rowB0 + r0 + 64) * CDIM + k0 + kk);
  };

  STAGE(0, 0, 0);
  __syncthreads();
  int cur = 0;

  for (int ct = 0; ct < 3; ct++) {
    const int rowA0 = ct * 128;
    f32x4 acc[4][4];
#pragma unroll
    for (int i = 0; i < 4; i++)
#pragma unroll
      for (int j = 0; j < 4; j++) acc[i][j] = (f32x4){0.f, 0.f, 0.f, 0.f};

    for (int k = 0; k < 12; k++) {
      if (!(ct == 2 && k == 11)) {
        int kn = k + 1, cn = ct;
        if (kn == 12) { kn = 0; cn = ct + 1; }
        STAGE(cn, kn, cur ^ 1);
      }
      const bf16_t* Ac = As + cur * 4096;
      const bf16_t* Bc = Bs + cur * 4096;
      bf16x8 af[4], bfr[4];
#pragma unroll
      for (int i = 0; i < 4; i++) {
        af[i]  = *(const bf16x8*)&Ac[(wr * 64 + i * 16 + l16) * 32 + q4 * 8];
        bfr[i] = *(const bf16x8*)&Bc[(wc * 64 + i * 16 + l16) * 32 + q4 * 8];
      }
#pragma unroll
      for (int i = 0; i < 4; i++)
#pragma unroll
        for (int j = 0; j < 4; j++) acc[i][j] = mfma16(af[i], bfr[j], acc[i][j]);
      __syncthreads();
      cur ^= 1;
    }

#pragma unroll
    for (int i = 0; i < 4; i++) {
      const int cg = rowA0 + wr * 64 + i * 16 + q4 * 4;
      float bv[4];
#pragma unroll
      for (int r = 0; r < 4; r++)
        bv[r] = isb ? (float)((const bf16_t*)bias)[cg + r] : ((const float*)bias)[cg + r];
#pragma unroll
      for (int j = 0; j < 4; j++) {
        const int ng = rowB0 + wc * 64 + j * 16 + l16;
        const int oi = (b * NTOK + ng) * CDIM + cg;
        if (isb) {
          bf16x4 o = {(bf16_t)(acc[i][j][0] + bv[0]), (bf16_t)(acc[i][j][1] + bv[1]),
                      (bf16_t)(acc[i][j][2] + bv[2]), (bf16_t)(acc[i][j][3] + bv[3])};
          *(bf16x4*)((bf16_t*)out + oi) = o;
        } else {
          f32x4 o = {acc[i][j][0] + bv[0], acc[i][j][1] + bv[1],
                     acc[i][j][2] + bv[2], acc[i][j][3] + bv[3]};
          *(f32x4*)((float*)out + oi) = o;
        }
      }
    }
  }
}

extern "C" void kernel_launch(void* const* d_in, const int* in_sizes, int n_in,
                              void* d_out, int out_size, void* d_ws, size_t ws_size,
                              hipStream_t stream) {
  (void)in_sizes; (void)n_in; (void)out_size;
  const void* X    = d_in[0];
  const void* Wqkv = d_in[1];
  const void* Wp   = d_in[2];
  const void* bias = d_in[3];

  char* ws = (char*)d_ws;
  bf16_t* qkv    = (bf16_t*)ws;                     // 3*WH bf16 = 150,994,944 B
  float*  S_acc  = (float*)(ws + 150994944);        // 64*2304 f32
  float*  ssq    = (float*)(ws + 151584768);        // 64*96 f32
  float*  attn_f = (float*)(ws + 151609344);        // 64*2304 f32
  bf16_t* Weff   = (bf16_t*)(ws + 152199168);       // 8*384*384 bf16
  int*    flag   = (int*)(ws + 154558464);
  bf16_t* Xb     = (bf16_t*)(ws + 154558720);       // 50,331,648 B
  bf16_t* Wb     = (bf16_t*)(ws + 204890368);       // 884,736 B -> end 205,775,104

  const bool have_cvt_ws = ws_size >= 205775104ULL;

  k_probe<<<dim3(1), 256, 0, stream>>>((const uint32_t*)X, flag);
  k_zero<<<dim3(600), 256, 0, stream>>>(S_acc, 153600);
  if (have_cvt_ws) {
    k_cvt<<<dim3(2048), 256, 0, stream>>>(X, Wqkv, Xb, Wb, flag);
    k_gemm_qkv<<<dim3(512), 256, 0, stream>>>(Xb, Wb, qkv);
  } else {
    k_gemm_qkv_bf16<<<dim3(512), 256, 0, stream>>>(X, Wqkv, qkv, flag);
    k_gemm_qkv_f32<<<dim3(512), 256, 0, stream>>>(X, Wqkv, qkv, flag);
  }
  k_gram<<<dim3(8, 64), 256, 0, stream>>>(qkv, S_acc, ssq);
  k_softmax<<<dim3(64), 64, 0, stream>>>(S_acc, ssq, attn_f);
  k_weff<<<dim3(512), 256, 0, stream>>>(attn_f, Wp, Weff, flag);
  k_gemm_out<<<dim3(64, 8), 256, 0, stream>>>(Weff, qkv, bias, d_out, flag);
}

// Round 10
// 394.047 us; speedup vs baseline: 1.0374x; 1.0374x over previous
//
#include <hip/hip_runtime.h>
#include <hip/hip_bf16.h>
#include <stdint.h>

// XCA (cross-covariance attention), B=8 N=8192 C=384 H=8 Dh=48.
// R13: R12's 2-phase dbuf was null (-8%): __syncthreads = vmcnt(0)+barrier
// drains the prefetch it was meant to hide. All barrier-per-k-step variants
// land at 131-143us. Fix: BARRIER-FREE k-loop.
//   - k_cvt writes X,Wqkv in MFMA-frag tile layout (16x32 tiles, tile*512+
//     lane*8): every fragment = one coalesced 16B/lane load.
//   - k_gemm_qkv: block = 64 tokens; stage block's B-slice (48KB, contiguous
//     in frag layout) to LDS ONCE (1 barrier); k-loop = af global (L2-hot,
//     A is 864KB L2-resident) + bfr LDS (conflict-free) + 8 MFMA. No barriers,
//     no re-reads of X -> 3 blocks/CU safe (no cache-thrash exposure).
//   - epilogue: swapped q/k -> bf16x4 along N; v -> bf16x4 along C (proven).
// K2/K3/K4/K5 unchanged from R12 (408us).

typedef __bf16 bf16_t;
typedef __attribute__((ext_vector_type(8))) __bf16 bf16x8;
typedef __attribute__((ext_vector_type(4))) __bf16 bf16x4;
typedef __attribute__((ext_vector_type(4))) float f32x4;

#define NTOK 8192
#define CDIM 384
#define WH   25165824   // 8*8*48*8192 elements per q/k plane
#define DHN  393216     // 48*8192

#define XCHUNKS 3145728   // 25,165,824 X elems / 8
#define TCHUNKS 3201024   // + 442,368 W elems / 8

__device__ __forceinline__ f32x4 mfma16(bf16x8 a, bf16x8 b, f32x4 c) {
  return __builtin_amdgcn_mfma_f32_16x16x32_bf16(a, b, c, 0, 0, 0);
}

// async global->LDS, 16B per lane (wave-uniform LDS base + lane*16; global
// address may be per-lane).
__device__ __forceinline__ void gload16(bf16_t* lds, const bf16_t* g) {
  __builtin_amdgcn_global_load_lds(
      (const __attribute__((address_space(1))) void*)g,
      (__attribute__((address_space(3))) void*)lds, 16, 0, 0);
}

template <bool BF16>
__device__ __forceinline__ bf16x8 load8(const void* p, int idx) {
  if constexpr (BF16) {
    return *(const bf16x8*)((const bf16_t*)p + idx);
  } else {
    const float* f = (const float*)p + idx;
    f32x4 a = *(const f32x4*)f;
    f32x4 b = *(const f32x4*)(f + 4);
    bf16x8 r;
    r[0] = (bf16_t)a[0]; r[1] = (bf16_t)a[1]; r[2] = (bf16_t)a[2]; r[3] = (bf16_t)a[3];
    r[4] = (bf16_t)b[0]; r[5] = (bf16_t)b[1]; r[6] = (bf16_t)b[2]; r[7] = (bf16_t)b[3];
    return r;
  }
}

// ---------------- probe: are inputs bf16 (1) or f32 (0)? ----------------
__global__ void k_probe(const uint32_t* __restrict__ X, int* __restrict__ flag) {
  __shared__ int cnt;
  if (threadIdx.x == 0) cnt = 0;
  __syncthreads();
  const uint32_t w = X[threadIdx.x];
  const int e = (int)((w >> 7) & 0xFF);  // exponent of low-16 as bf16
  const int sane = (e >= 110 && e <= 131) ? 1 : 0;
  atomicAdd(&cnt, sane);
  __syncthreads();
  if (threadIdx.x == 0) *flag = (cnt >= 128) ? 1 : 0;
}

// ---------------- zero fp32 accumulators ----------------
__global__ void k_zero(float* __restrict__ p, int n) {
  int i = blockIdx.x * 256 + threadIdx.x;
  if (i < n) p[i] = 0.f;
}

// ---------------- cvt: X,Wqkv -> bf16 FRAG-TILE layout ----------------
// Frag layout: elem (row m, k) -> tile t = (m>>4)*12 + (k>>5);
// addr = t*512 + ((m&15) | (((k>>3)&3)<<4))*8 + (k&7).
// Chunk c (8 elems) = (t = c>>6, lane = c&63): m = (t/12)*16 + (lane&15),
// k = (t%12)*32 + ((lane>>4)<<3). Writes fully coalesced at dst + c*8.
__global__ void k_cvt(const void* __restrict__ X, const void* __restrict__ Wqkv,
                      bf16_t* __restrict__ Xf, bf16_t* __restrict__ Wf,
                      const int* __restrict__ flagp) {
  const int isb = *flagp;
  const int G = gridDim.x * 256;
  for (int c = blockIdx.x * 256 + threadIdx.x; c < TCHUNKS; c += G) {
    const bool isX = c < XCHUNKS;
    const int lc = isX ? c : c - XCHUNKS;
    const int t = lc >> 6, ln = lc & 63;
    const int tm = t / 12, tk = t - tm * 12;
    const int m = tm * 16 + (ln & 15);
    const int k = tk * 32 + ((ln >> 4) << 3);
    const int off = m * CDIM + k;
    const void* src = isX ? X : Wqkv;
    bf16_t* dst = (isX ? Xf : Wf) + (size_t)lc * 8;
    if (isb) {
      *(bf16x8*)dst = *(const bf16x8*)((const bf16_t*)src + off);
    } else {
      const float* f = (const float*)src + off;
      const f32x4 a = *(const f32x4*)f;
      const f32x4 b = *(const f32x4*)(f + 4);
      bf16x8 r;
      r[0] = (bf16_t)a[0]; r[1] = (bf16_t)a[1]; r[2] = (bf16_t)a[2]; r[3] = (bf16_t)a[3];
      r[4] = (bf16_t)b[0]; r[5] = (bf16_t)b[1]; r[6] = (bf16_t)b[2]; r[7] = (bf16_t)b[3];
      *(bf16x8*)dst = r;
    }
  }
}

// ---------------- K1: qkv = x @ w_qkv^T (barrier-free frag GEMM) ----------------
// Grid (1024): block = 64 tokens. B-slice (64 tok x 384 k = 48 KB, contiguous
// in frag layout) staged to LDS once. k-loop: af from global frag (L2-hot),
// bfr from LDS frag (lane*16B contiguous, conflict-free), 8 MFMA. No barriers.
// Wave wv owns row-tiles {wv*2, wv*2+1} of each jt's 128 rows.
__global__ __launch_bounds__(256, 3) void k_gemm_qkv(
    const bf16_t* __restrict__ Xf, const bf16_t* __restrict__ Wf,
    bf16_t* __restrict__ qkv) {
  __shared__ __align__(16) bf16_t Bs[24576];  // 48 tiles * 512 elems = 48 KB

  const int tid = threadIdx.x;
  const int lane = tid & 63;
  const int wv = tid >> 6;            // 0..3
  const int q4 = lane >> 4, l16 = lane & 15;
  const int tok0 = blockIdx.x * 64;
  const int bb = tok0 >> 13;          // batch (64 | 8192 -> never crosses)
  const int nB = tok0 & 8191;         // token base within batch

  // stage B-slice: 3072 chunks of 8 elems, contiguous in frag layout.
  const bf16_t* Bsrc = Xf + (size_t)tok0 * CDIM;  // (tok0>>4)*12*512 == tok0*384
#pragma unroll
  for (int s = 0; s < 12; s++) {
    const int chunk = s * 256 + tid;
    gload16(Bs + chunk * 8, Bsrc + chunk * 8);
  }
  __syncthreads();  // drains vmcnt; Bs complete + visible. Read-only after.

  for (int jt = 0; jt < 9; jt++) {
    const int which = jt / 3;         // 0=q 1=k 2=v (uniform per jt)
    const int jtt = jt - which * 3;
    f32x4 acc[2][4];
#pragma unroll
    for (int i = 0; i < 2; i++)
#pragma unroll
      for (int j = 0; j < 4; j++) acc[i][j] = (f32x4){0.f, 0.f, 0.f, 0.f};

    const int rt0 = jt * 8 + wv * 2;  // this wave's first A row-tile (of 72)
#pragma unroll 2
    for (int kc = 0; kc < 12; kc++) {
      bf16x8 af[2], bfr[4];
#pragma unroll
      for (int i = 0; i < 2; i++)
        af[i] = *(const bf16x8*)(Wf + (size_t)((rt0 + i) * 12 + kc) * 512 + lane * 8);
#pragma unroll
      for (int j = 0; j < 4; j++)
        bfr[j] = *(const bf16x8*)&Bs[(j * 12 + kc) * 512 + lane * 8];
      if (which < 2) {
#pragma unroll
        for (int i = 0; i < 2; i++)
#pragma unroll
          for (int j = 0; j < 4; j++) acc[i][j] = mfma16(bfr[j], af[i], acc[i][j]);
      } else {
#pragma unroll
        for (int i = 0; i < 2; i++)
#pragma unroll
          for (int j = 0; j < 4; j++) acc[i][j] = mfma16(af[i], bfr[j], acc[i][j]);
      }
    }

    if (which < 2) {
      // swapped: acc[i][j][r] = D[token = nB + j*16 + q4*4 + r][ch = jtt*128 + wv*32 + i*16 + l16]
#pragma unroll
      for (int i = 0; i < 2; i++) {
        const int rin = jtt * 128 + wv * 32 + i * 16 + l16;  // channel in plane
        const int h = rin / 48, dh = rin - h * 48;
        bf16_t* rowp = qkv + which * WH + (bb * 8 + h) * DHN + dh * NTOK
                       + nB + q4 * 4;
#pragma unroll
        for (int j = 0; j < 4; j++) {
          bf16x4 o = {(bf16_t)acc[i][j][0], (bf16_t)acc[i][j][1],
                      (bf16_t)acc[i][j][2], (bf16_t)acc[i][j][3]};
          *(bf16x4*)(rowp + j * 16) = o;
        }
      }
    } else {
      // original: acc[i][j][r] = D[ch = jtt*128 + wv*32 + i*16 + q4*4 + r][token = tok0 + j*16 + l16]
#pragma unroll
      for (int i = 0; i < 2; i++) {
        const int c0 = jtt * 128 + wv * 32 + i * 16 + q4 * 4;
#pragma unroll
        for (int j = 0; j < 4; j++) {
          const int mg = tok0 + j * 16 + l16;
          bf16x4 o = {(bf16_t)acc[i][j][0], (bf16_t)acc[i][j][1],
                      (bf16_t)acc[i][j][2], (bf16_t)acc[i][j][3]};
          *(bf16x4*)(qkv + 2 * WH + (size_t)mg * CDIM + c0) = o;
        }
      }
    }
  }
}

// ---------------- fallback path (ws too small): legacy 2-barrier reg-staging --
template <bool BF16>
__device__ __forceinline__ void qkv_body_legacy(const void* __restrict__ X,
                                                const void* __restrict__ Wqkv,
                                                bf16_t* __restrict__ qkv,
                                                bf16_t* As, bf16_t* Bs) {
  const int tid = threadIdx.x;
  const int lane = tid & 63;
  const int wr = tid >> 7, wc = (tid >> 6) & 1;
  const int q4 = lane >> 4, l16 = lane & 15;
  const int rowB0 = blockIdx.x * 128;
  const int r0 = tid >> 2, kk = (tid & 3) << 3;
  const int bb = rowB0 >> 13;
  const int nB = rowB0 & 8191;

  for (int jt = 0; jt < 9; jt++) {
    const int rowA0 = jt * 128;
    const int which = jt / 3;
    const int jtt = jt - which * 3;
    f32x4 acc[4][4];
#pragma unroll
    for (int i = 0; i < 4; i++)
#pragma unroll
      for (int j = 0; j < 4; j++) acc[i][j] = (f32x4){0.f, 0.f, 0.f, 0.f};

    for (int k0 = 0; k0 < CDIM; k0 += 32) {
      bf16x8 a0 = load8<BF16>(Wqkv, (rowA0 + r0) * CDIM + k0 + kk);
      bf16x8 a1 = load8<BF16>(Wqkv, (rowA0 + r0 + 64) * CDIM + k0 + kk);
      bf16x8 b0 = load8<BF16>(X, (rowB0 + r0) * CDIM + k0 + kk);
      bf16x8 b1 = load8<BF16>(X, (rowB0 + r0 + 64) * CDIM + k0 + kk);
      __syncthreads();
      *(bf16x8*)&As[tid * 8] = a0;
      *(bf16x8*)&As[(tid + 256) * 8] = a1;
      *(bf16x8*)&Bs[tid * 8] = b0;
      *(bf16x8*)&Bs[(tid + 256) * 8] = b1;
      __syncthreads();
      bf16x8 af[4], bfr[4];
#pragma unroll
      for (int i = 0; i < 4; i++) {
        af[i]  = *(const bf16x8*)&As[(wr * 64 + i * 16 + l16) * 32 + q4 * 8];
        bfr[i] = *(const bf16x8*)&Bs[(wc * 64 + i * 16 + l16) * 32 + q4 * 8];
      }
      if (which < 2) {
#pragma unroll
        for (int i = 0; i < 4; i++)
#pragma unroll
          for (int j = 0; j < 4; j++) acc[i][j] = mfma16(bfr[j], af[i], acc[i][j]);
      } else {
#pragma unroll
        for (int i = 0; i < 4; i++)
#pragma unroll
          for (int j = 0; j < 4; j++) acc[i][j] = mfma16(af[i], bfr[j], acc[i][j]);
      }
    }

    if (which < 2) {
#pragma unroll
      for (int i = 0; i < 4; i++) {
        const int rin = jtt * 128 + wr * 64 + i * 16 + l16;
        const int h = rin / 48, dh = rin - h * 48;
        bf16_t* rowp = qkv + which * WH + (bb * 8 + h) * DHN + dh * NTOK
                       + nB + wc * 64 + q4 * 4;
#pragma unroll
        for (int j = 0; j < 4; j++) {
          bf16x4 o = {(bf16_t)acc[i][j][0], (bf16_t)acc[i][j][1],
                      (bf16_t)acc[i][j][2], (bf16_t)acc[i][j][3]};
          *(bf16x4*)(rowp + j * 16) = o;
        }
      }
    } else {
#pragma unroll
      for (int i = 0; i < 4; i++) {
        const int rin0 = jtt * 128 + wr * 64 + i * 16 + q4 * 4;
#pragma unroll
        for (int j = 0; j < 4; j++) {
          const int mg = rowB0 + wc * 64 + j * 16 + l16;
          bf16x4 o = {(bf16_t)acc[i][j][0], (bf16_t)acc[i][j][1],
                      (bf16_t)acc[i][j][2], (bf16_t)acc[i][j][3]};
          *(bf16x4*)(qkv + 2 * WH + mg * CDIM + rin0) = o;
        }
      }
    }
  }
}

__global__ __launch_bounds__(256, 2) void k_gemm_qkv_bf16(
    const void* __restrict__ X, const void* __restrict__ Wqkv,
    bf16_t* __restrict__ qkv, const int* __restrict__ flagp) {
  __shared__ __align__(16) bf16_t As[128 * 32];
  __shared__ __align__(16) bf16_t Bs[128 * 32];
  if (!*flagp) return;
  qkv_body_legacy<true>(X, Wqkv, qkv, As, Bs);
}

__global__ __launch_bounds__(256, 2) void k_gemm_qkv_f32(
    const void* __restrict__ X, const void* __restrict__ Wqkv,
    bf16_t* __restrict__ qkv, const int* __restrict__ flagp) {
  __shared__ __align__(16) bf16_t As[128 * 32];
  __shared__ __align__(16) bf16_t Bs[128 * 32];
  if (*flagp) return;
  qkv_body_legacy<false>(X, Wqkv, qkv, As, Bs);
}

// ---------------- K2: Gram S=Q K^T + sumsq ----------------
__global__ __launch_bounds__(256, 2) void k_gram(
    const bf16_t* __restrict__ qkv, float* __restrict__ S_acc, float* __restrict__ ssq_acc) {
  __shared__ __align__(16) float sm[9312];  // 37,248 B
  bf16_t* Qs = (bf16_t*)sm;                 // 6144 bf16 = [4][48][32]
  bf16_t* Ks = Qs + 6144;
  float* ssq_sm = sm + 9216;                // 96 floats

  const int tid = threadIdx.x;
  const int wave = tid >> 6, lane = tid & 63, q4 = lane >> 4, l16 = lane & 15;
  const int s = blockIdx.x, bh = blockIdx.y;
  const bf16_t* Qg = qkv + bh * DHN;
  const bf16_t* Kg = qkv + WH + bh * DHN;

  if (tid < 96) ssq_sm[tid] = 0.f;

  f32x4 acc[3][3];
#pragma unroll
  for (int i = 0; i < 3; i++)
#pragma unroll
    for (int j = 0; j < 3; j++) acc[i][j] = (f32x4){0.f, 0.f, 0.f, 0.f};
  float qss[3] = {0.f, 0.f, 0.f}, kss[3] = {0.f, 0.f, 0.f};

  for (int t0 = 0; t0 < 8; t0++) {
    const int n0 = s * 1024 + t0 * 128;
    bf16x8 qv[3], kv[3];
#pragma unroll
    for (int jj = 0; jj < 3; jj++) {
      const int c = jj * 256 + tid;
      const int st = c / 192, rem = c - st * 192;
      const int row = rem >> 2, kk = (rem & 3) << 3;
      const int gofs = row * NTOK + n0 + st * 32 + kk;
      qv[jj] = *(const bf16x8*)(Qg + gofs);
      kv[jj] = *(const bf16x8*)(Kg + gofs);
    }
    __syncthreads();
#pragma unroll
    for (int jj = 0; jj < 3; jj++) {
      *(bf16x8*)&Qs[(jj * 256 + tid) * 8] = qv[jj];
      *(bf16x8*)&Ks[(jj * 256 + tid) * 8] = kv[jj];
    }
    __syncthreads();
    bf16x8 qf[3], kf[3];
#pragma unroll
    for (int i = 0; i < 3; i++) {
      qf[i] = *(const bf16x8*)&Qs[wave * 1536 + (i * 16 + l16) * 32 + q4 * 8];
      kf[i] = *(const bf16x8*)&Ks[wave * 1536 + (i * 16 + l16) * 32 + q4 * 8];
    }
#pragma unroll
    for (int i = 0; i < 3; i++) {
#pragma unroll
      for (int u = 0; u < 8; u++) {
        const float qv2 = (float)qf[i][u], kv2 = (float)kf[i][u];
        qss[i] += qv2 * qv2;
        kss[i] += kv2 * kv2;
      }
#pragma unroll
      for (int j = 0; j < 3; j++) acc[i][j] = mfma16(qf[i], kf[j], acc[i][j]);
    }
  }

  __syncthreads();
  float* red = sm;  // 4 waves x 2304 fp32
#pragma unroll
  for (int i = 0; i < 3; i++)
#pragma unroll
    for (int j = 0; j < 3; j++)
#pragma unroll
      for (int r = 0; r < 4; r++)
        red[wave * 2304 + (i * 3 + j) * 256 + lane * 4 + r] = acc[i][j][r];
#pragma unroll
  for (int i = 0; i < 3; i++) {
    atomicAdd(&ssq_sm[i * 16 + l16], qss[i]);
    atomicAdd(&ssq_sm[48 + i * 16 + l16], kss[i]);
  }
  __syncthreads();
  for (int idx = tid; idx < 2304; idx += 256) {
    const float v = red[idx] + red[2304 + idx] + red[4608 + idx] + red[6912 + idx];
    const int tile = idx >> 8, ln = (idx >> 2) & 63, r = idx & 3;
    const int i = tile / 3, j = tile - i * 3;
    const int d = i * 16 + ((ln >> 4) << 2) + r;
    const int e = j * 16 + (ln & 15);
    atomicAdd(&S_acc[bh * 2304 + d * 48 + e], v);
  }
  if (tid < 96) atomicAdd(&ssq_acc[bh * 96 + tid], ssq_sm[tid]);
}

// ---------------- K3: softmax(S / (|q_d||k_e|)) ----------------
__global__ void k_softmax(const float* __restrict__ S_acc, const float* __restrict__ ssq_acc,
                          float* __restrict__ attn_f) {
  __shared__ float invk_sm[48];
  const int bh = blockIdx.x, d = threadIdx.x;
  if (d < 48) invk_sm[d] = 1.f / fmaxf(sqrtf(ssq_acc[bh * 96 + 48 + d]), 1e-12f);
  __syncthreads();
  if (d < 48) {
    const float invq = 1.f / fmaxf(sqrtf(ssq_acc[bh * 96 + d]), 1e-12f);
    float lg[48], mx = -1e30f;
#pragma unroll
    for (int e = 0; e < 48; e++) {
      lg[e] = S_acc[bh * 2304 + d * 48 + e] * invq * invk_sm[e];
      mx = fmaxf(mx, lg[e]);
    }
    float ssum = 0.f;
#pragma unroll
    for (int e = 0; e < 48; e++) { lg[e] = expf(lg[e] - mx); ssum += lg[e]; }
    const float inv = 1.f / ssum;
#pragma unroll
    for (int e = 0; e < 48; e++) attn_f[bh * 2304 + d * 48 + e] = lg[e] * inv;
  }
}

// ---------------- K4: Weff_b[c'][h*48+e] = sum_d Wp[c'][h*48+d] attn[bh][d][e] ------
// Register-tiny LDS-tile formulation (R10, 162us -> ~10us).
__global__ void k_weff(
    const float* __restrict__ attn_f, const void* __restrict__ Wp,
    bf16_t* __restrict__ Weff, const int* __restrict__ flagp) {
  __shared__ float a_sm[2304];  // attn[d][e]
  __shared__ float w_sm[2304];  // Wp[c'_local][d]
  const int isb = *flagp;
  const int bid = blockIdx.x;
  const int ct = bid & 7, h = (bid >> 3) & 7, b = bid >> 6;
  const int bh = b * 8 + h;
  const int tid = threadIdx.x;

  for (int i = tid; i < 2304; i += 256) {
    a_sm[i] = attn_f[bh * 2304 + i];
    const int r = i / 48, c = i - r * 48;
    const int gi = (ct * 48 + r) * CDIM + h * 48 + c;
    w_sm[i] = isb ? (float)((const bf16_t*)Wp)[gi] : ((const float*)Wp)[gi];
  }
  __syncthreads();

  for (int o = tid; o < 2304; o += 256) {
    const int r = o / 48, e = o - r * 48;
    float s = 0.f;
#pragma unroll 8
    for (int d = 0; d < 48; d++) s += w_sm[r * 48 + d] * a_sm[d * 48 + e];
    Weff[b * 147456 + (ct * 48 + r) * CDIM + h * 48 + e] = (bf16_t)s;
  }
}

// ---------------- K5: out[b,n,c'] = sum_c Weff_b[c'][c] V[b,n,c] + bias[c'] --------
// Grid (64 nt, 8 b); ct=0..2 inside; 2 blocks/CU; pipelined dbuf (36 steps).
__global__ __launch_bounds__(256, 2) void k_gemm_out(
    const bf16_t* __restrict__ Weff, const bf16_t* __restrict__ qkv,
    const void* __restrict__ bias, void* __restrict__ out, const int* __restrict__ flagp) {
  __shared__ __align__(16) bf16_t As[2 * 4096];
  __shared__ __align__(16) bf16_t Bs[2 * 4096];
  const int isb = *flagp;
  const int tid = threadIdx.x;
  const int lane = tid & 63;
  const int wr = tid >> 7, wc = (tid >> 6) & 1;
  const int q4 = lane >> 4, l16 = lane & 15;
  const int b = blockIdx.y;
  const int rowB0 = blockIdx.x * 128;  // n tile
  const bf16_t* Aa = Weff + b * 147456;
  const bf16_t* Ba = qkv + 2 * WH + b * (NTOK * CDIM);
  const int r0 = tid >> 2, kk = (tid & 3) << 3;

  auto STAGE = [&](int cts, int ks, int nxt) {
    const int rowA0 = cts * 128;
    const int k0 = ks * 32;
    bf16_t* Ad = As + nxt * 4096;
    bf16_t* Bd = Bs + nxt * 4096;
    gload16(Ad + tid * 8,         Aa + (rowA0 + r0) * CDIM + k0 + kk);
    gload16(Ad + (tid + 256) * 8, Aa + (rowA0 + r0 + 64) * CDIM + k0 + kk);
    gload16(Bd + tid * 8,         Ba + (rowB0 + r0) * CDIM + k0 + kk);
    gload16(Bd + (tid + 256) * 8, Ba + (rowB0 + r0 + 64) * CDIM + k0 + kk);
  };

  STAGE(0, 0, 0);
  __syncthreads();
  int cur = 0;

  for (int ct = 0; ct < 3; ct++) {
    const int rowA0 = ct * 128;
    f32x4 acc[4][4];
#pragma unroll
    for (int i = 0; i < 4; i++)
#pragma unroll
      for (int j = 0; j < 4; j++) acc[i][j] = (f32x4){0.f, 0.f, 0.f, 0.f};

    for (int k = 0; k < 12; k++) {
      if (!(ct == 2 && k == 11)) {
        int kn = k + 1, cn = ct;
        if (kn == 12) { kn = 0; cn = ct + 1; }
        STAGE(cn, kn, cur ^ 1);
      }
      const bf16_t* Ac = As + cur * 4096;
      const bf16_t* Bc = Bs + cur * 4096;
      bf16x8 af[4], bfr[4];
#pragma unroll
      for (int i = 0; i < 4; i++) {
        af[i]  = *(const bf16x8*)&Ac[(wr * 64 + i * 16 + l16) * 32 + q4 * 8];
        bfr[i] = *(const bf16x8*)&Bc[(wc * 64 + i * 16 + l16) * 32 + q4 * 8];
      }
#pragma unroll
      for (int i = 0; i < 4; i++)
#pragma unroll
        for (int j = 0; j < 4; j++) acc[i][j] = mfma16(af[i], bfr[j], acc[i][j]);
      __syncthreads();
      cur ^= 1;
    }

#pragma unroll
    for (int i = 0; i < 4; i++) {
      const int cg = rowA0 + wr * 64 + i * 16 + q4 * 4;
      float bv[4];
#pragma unroll
      for (int r = 0; r < 4; r++)
        bv[r] = isb ? (float)((const bf16_t*)bias)[cg + r] : ((const float*)bias)[cg + r];
#pragma unroll
      for (int j = 0; j < 4; j++) {
        const int ng = rowB0 + wc * 64 + j * 16 + l16;
        const int oi = (b * NTOK + ng) * CDIM + cg;
        if (isb) {
          bf16x4 o = {(bf16_t)(acc[i][j][0] + bv[0]), (bf16_t)(acc[i][j][1] + bv[1]),
                      (bf16_t)(acc[i][j][2] + bv[2]), (bf16_t)(acc[i][j][3] + bv[3])};
          *(bf16x4*)((bf16_t*)out + oi) = o;
        } else {
          f32x4 o = {acc[i][j][0] + bv[0], acc[i][j][1] + bv[1],
                     acc[i][j][2] + bv[2], acc[i][j][3] + bv[3]};
          *(f32x4*)((float*)out + oi) = o;
        }
      }
    }
  }
}

extern "C" void kernel_launch(void* const* d_in, const int* in_sizes, int n_in,
                              void* d_out, int out_size, void* d_ws, size_t ws_size,
                              hipStream_t stream) {
  (void)in_sizes; (void)n_in; (void)out_size;
  const void* X    = d_in[0];
  const void* Wqkv = d_in[1];
  const void* Wp   = d_in[2];
  const void* bias = d_in[3];

  char* ws = (char*)d_ws;
  bf16_t* qkv    = (bf16_t*)ws;                     // 3*WH bf16 = 150,994,944 B
  float*  S_acc  = (float*)(ws + 150994944);        // 64*2304 f32
  float*  ssq    = (float*)(ws + 151584768);        // 64*96 f32
  float*  attn_f = (float*)(ws + 151609344);        // 64*2304 f32
  bf16_t* Weff   = (bf16_t*)(ws + 152199168);       // 8*384*384 bf16
  int*    flag   = (int*)(ws + 154558464);
  bf16_t* Xf     = (bf16_t*)(ws + 154558720);       // 50,331,648 B (frag layout)
  bf16_t* Wf     = (bf16_t*)(ws + 204890368);       // 884,736 B -> end 205,775,104

  const bool have_cvt_ws = ws_size >= 205775104ULL;

  k_probe<<<dim3(1), 256, 0, stream>>>((const uint32_t*)X, flag);
  k_zero<<<dim3(600), 256, 0, stream>>>(S_acc, 153600);
  if (have_cvt_ws) {
    k_cvt<<<dim3(2048), 256, 0, stream>>>(X, Wqkv, Xf, Wf, flag);
    k_gemm_qkv<<<dim3(1024), 256, 0, stream>>>(Xf, Wf, qkv);
  } else {
    k_gemm_qkv_bf16<<<dim3(512), 256, 0, stream>>>(X, Wqkv, qkv, flag);
    k_gemm_qkv_f32<<<dim3(512), 256, 0, stream>>>(X, Wqkv, qkv, flag);
  }
  k_gram<<<dim3(8, 64), 256, 0, stream>>>(qkv, S_acc, ssq);
  k_softmax<<<dim3(64), 64, 0, stream>>>(S_acc, ssq, attn_f);
  k_weff<<<dim3(512), 256, 0, stream>>>(attn_f, Wp, Weff, flag);
  k_gemm_out<<<dim3(64, 8), 256, 0, stream>>>(Weff, qkv, bias, d_out, flag);
}

// Round 12
// 389.841 us; speedup vs baseline: 1.0486x; 1.0108x over previous
//
#include <hip/hip_runtime.h>
#include <hip/hip_bf16.h>
#include <stdint.h>

// XCA (cross-covariance attention), B=8 N=8192 C=384 H=8 Dh=48.
// R15 == R14 resubmit (R14 bench was an infra failure, "container failed
// twice"; kernel never executed — same signature as R6, whose verbatim
// resubmit ran fine). Audit found no hang/fault vector. Theory unchanged:
// propagate R13's barrier-free frag-GEMM pattern to k_gram + k_gemm_out.
//   - Q/K planes stored FRAG-TILED (k=token): k_gram reads frags direct from
//     global (coalesced, streamed once), 0 k-loop barriers; ssq computed via
//     mfma(qf,qf)/mfma(kf,kf) diagonal (kills the 96-VALU-per-chunk hotspot).
//   - V frag-tiled per batch; Weff frag-tiled by k_weff: k_gemm_out = clone of
//     R13 qkv (stage 48KB V-slice once, Weff L2-resident global frags,
//     barrier-free k-loop, 3 blocks/CU).
// Frag layout for row-major [R][K]: tile t=(r>>4)*(K/32)+(k>>5);
// word w=(r&15)|(((k>>3)&3)<<4); elem addr = t*512 + w*8 + (k&7).
// R13 verified: frag read = tile*512 + lane*8 (16B/lane, conflict/coalesce-perfect).

typedef __bf16 bf16_t;
typedef __attribute__((ext_vector_type(8))) __bf16 bf16x8;
typedef __attribute__((ext_vector_type(4))) __bf16 bf16x4;
typedef __attribute__((ext_vector_type(4))) float f32x4;

#define NTOK 8192
#define CDIM 384
#define WH   25165824   // 8*8*48*8192 elements per q/k plane
#define DHN  393216     // 48*8192 (plane elems = 768 tiles * 512)

#define XCHUNKS 3145728   // 25,165,824 X elems / 8
#define TCHUNKS 3201024   // + 442,368 W elems / 8

__device__ __forceinline__ f32x4 mfma16(bf16x8 a, bf16x8 b, f32x4 c) {
  return __builtin_amdgcn_mfma_f32_16x16x32_bf16(a, b, c, 0, 0, 0);
}

__device__ __forceinline__ void gload16(bf16_t* lds, const bf16_t* g) {
  __builtin_amdgcn_global_load_lds(
      (const __attribute__((address_space(1))) void*)g,
      (__attribute__((address_space(3))) void*)lds, 16, 0, 0);
}

template <bool BF16>
__device__ __forceinline__ bf16x8 load8(const void* p, int idx) {
  if constexpr (BF16) {
    return *(const bf16x8*)((const bf16_t*)p + idx);
  } else {
    const float* f = (const float*)p + idx;
    f32x4 a = *(const f32x4*)f;
    f32x4 b = *(const f32x4*)(f + 4);
    bf16x8 r;
    r[0] = (bf16_t)a[0]; r[1] = (bf16_t)a[1]; r[2] = (bf16_t)a[2]; r[3] = (bf16_t)a[3];
    r[4] = (bf16_t)b[0]; r[5] = (bf16_t)b[1]; r[6] = (bf16_t)b[2]; r[7] = (bf16_t)b[3];
    return r;
  }
}

// ---------------- probe ----------------
__global__ void k_probe(const uint32_t* __restrict__ X, int* __restrict__ flag) {
  __shared__ int cnt;
  if (threadIdx.x == 0) cnt = 0;
  __syncthreads();
  const uint32_t w = X[threadIdx.x];
  const int e = (int)((w >> 7) & 0xFF);
  const int sane = (e >= 110 && e <= 131) ? 1 : 0;
  atomicAdd(&cnt, sane);
  __syncthreads();
  if (threadIdx.x == 0) *flag = (cnt >= 128) ? 1 : 0;
}

// ---------------- zero fp32 accumulators ----------------
__global__ void k_zero(float* __restrict__ p, int n) {
  int i = blockIdx.x * 256 + threadIdx.x;
  if (i < n) p[i] = 0.f;
}

// ---------------- cvt: X,Wqkv -> bf16 FRAG-TILE layout ----------------
__global__ void k_cvt(const void* __restrict__ X, const void* __restrict__ Wqkv,
                      bf16_t* __restrict__ Xf, bf16_t* __restrict__ Wf,
                      const int* __restrict__ flagp) {
  const int isb = *flagp;
  const int G = gridDim.x * 256;
  for (int c = blockIdx.x * 256 + threadIdx.x; c < TCHUNKS; c += G) {
    const bool isX = c < XCHUNKS;
    const int lc = isX ? c : c - XCHUNKS;
    const int t = lc >> 6, ln = lc & 63;
    const int tm = t / 12, tk = t - tm * 12;
    const int m = tm * 16 + (ln & 15);
    const int k = tk * 32 + ((ln >> 4) << 3);
    const int off = m * CDIM + k;
    const void* src = isX ? X : Wqkv;
    bf16_t* dst = (isX ? Xf : Wf) + (size_t)lc * 8;
    if (isb) {
      *(bf16x8*)dst = *(const bf16x8*)((const bf16_t*)src + off);
    } else {
      const float* f = (const float*)src + off;
      const f32x4 a = *(const f32x4*)f;
      const f32x4 b = *(const f32x4*)(f + 4);
      bf16x8 r;
      r[0] = (bf16_t)a[0]; r[1] = (bf16_t)a[1]; r[2] = (bf16_t)a[2]; r[3] = (bf16_t)a[3];
      r[4] = (bf16_t)b[0]; r[5] = (bf16_t)b[1]; r[6] = (bf16_t)b[2]; r[7] = (bf16_t)b[3];
      *(bf16x8*)dst = r;
    }
  }
}

// ---- frag-store helpers for qkv epilogues (both main + legacy paths) ----
// q/k plane (k=token): elem (dh, tok) -> t=(dh>>4)*256+(tok>>5), w=(dh&15)|(((tok>>3)&3)<<4)
__device__ __forceinline__ void store_qk4(bf16_t* plane, int dh, int tok0, bf16x4 o) {
  const int t = (dh >> 4) * 256 + (tok0 >> 5);
  const int w = (dh & 15) | (((tok0 >> 3) & 3) << 4);
  *(bf16x4*)(plane + t * 512 + w * 8 + (tok0 & 7)) = o;
}
// V per batch (k=channel): elem (tok, c) -> t=(tok>>4)*12+(c>>5), w=(tok&15)|(((c>>3)&3)<<4)
__device__ __forceinline__ void store_v4(bf16_t* vb, int tok, int c0, bf16x4 o) {
  const int t = (tok >> 4) * 12 + (c0 >> 5);
  const int w = (tok & 15) | (((c0 >> 3) & 3) << 4);
  *(bf16x4*)(vb + t * 512 + w * 8 + (c0 & 7)) = o;
}

// ---------------- K1: qkv = x @ w_qkv^T (barrier-free frag GEMM) ----------------
// Grid (1024): block = 64 tokens; B-slice (48KB frag-contig) staged once.
// q/k outputs frag-tiled into planes; v frag-tiled per batch.
__global__ __launch_bounds__(256, 3) void k_gemm_qkv(
    const bf16_t* __restrict__ Xf, const bf16_t* __restrict__ Wf,
    bf16_t* __restrict__ qkv) {
  __shared__ __align__(16) bf16_t Bs[24576];  // 48 tiles * 512

  const int tid = threadIdx.x;
  const int lane = tid & 63;
  const int wv = tid >> 6;
  const int q4 = lane >> 4, l16 = lane & 15;
  const int tok0 = blockIdx.x * 64;
  const int bb = tok0 >> 13;
  const int nB = tok0 & 8191;

  const bf16_t* Bsrc = Xf + (size_t)tok0 * CDIM;
#pragma unroll
  for (int s = 0; s < 12; s++) {
    const int chunk = s * 256 + tid;
    gload16(Bs + chunk * 8, Bsrc + chunk * 8);
  }
  __syncthreads();

  bf16_t* vb = qkv + 2 * WH + (size_t)bb * (NTOK * CDIM);

  for (int jt = 0; jt < 9; jt++) {
    const int which = jt / 3;
    const int jtt = jt - which * 3;
    f32x4 acc[2][4];
#pragma unroll
    for (int i = 0; i < 2; i++)
#pragma unroll
      for (int j = 0; j < 4; j++) acc[i][j] = (f32x4){0.f, 0.f, 0.f, 0.f};

    const int rt0 = jt * 8 + wv * 2;
#pragma unroll 2
    for (int kc = 0; kc < 12; kc++) {
      bf16x8 af[2], bfr[4];
#pragma unroll
      for (int i = 0; i < 2; i++)
        af[i] = *(const bf16x8*)(Wf + (size_t)((rt0 + i) * 12 + kc) * 512 + lane * 8);
#pragma unroll
      for (int j = 0; j < 4; j++)
        bfr[j] = *(const bf16x8*)&Bs[(j * 12 + kc) * 512 + lane * 8];
      if (which < 2) {
#pragma unroll
        for (int i = 0; i < 2; i++)
#pragma unroll
          for (int j = 0; j < 4; j++) acc[i][j] = mfma16(bfr[j], af[i], acc[i][j]);
      } else {
#pragma unroll
        for (int i = 0; i < 2; i++)
#pragma unroll
          for (int j = 0; j < 4; j++) acc[i][j] = mfma16(af[i], bfr[j], acc[i][j]);
      }
    }

    if (which < 2) {
      // swapped: acc[i][j][r] = D[tok = nB + j*16 + q4*4 + r][ch = jtt*128 + wv*32 + i*16 + l16]
#pragma unroll
      for (int i = 0; i < 2; i++) {
        const int rin = jtt * 128 + wv * 32 + i * 16 + l16;
        const int h = rin / 48, dh = rin - h * 48;
        bf16_t* plane = qkv + which * WH + (size_t)(bb * 8 + h) * DHN;
#pragma unroll
        for (int j = 0; j < 4; j++) {
          bf16x4 o = {(bf16_t)acc[i][j][0], (bf16_t)acc[i][j][1],
                      (bf16_t)acc[i][j][2], (bf16_t)acc[i][j][3]};
          store_qk4(plane, dh, nB + j * 16 + q4 * 4, o);
        }
      }
    } else {
      // original: acc[i][j][r] = D[c = jtt*128 + wv*32 + i*16 + q4*4 + r][tok = nB + j*16 + l16]
#pragma unroll
      for (int i = 0; i < 2; i++) {
        const int c0 = jtt * 128 + wv * 32 + i * 16 + q4 * 4;
#pragma unroll
        for (int j = 0; j < 4; j++) {
          bf16x4 o = {(bf16_t)acc[i][j][0], (bf16_t)acc[i][j][1],
                      (bf16_t)acc[i][j][2], (bf16_t)acc[i][j][3]};
          store_v4(vb, nB + j * 16 + l16, c0, o);
        }
      }
    }
  }
}

// ---------------- fallback (ws too small): legacy staging, frag epilogues ----
template <bool BF16>
__device__ __forceinline__ void qkv_body_legacy(const void* __restrict__ X,
                                                const void* __restrict__ Wqkv,
                                                bf16_t* __restrict__ qkv,
                                                bf16_t* As, bf16_t* Bs) {
  const int tid = threadIdx.x;
  const int lane = tid & 63;
  const int wr = tid >> 7, wc = (tid >> 6) & 1;
  const int q4 = lane >> 4, l16 = lane & 15;
  const int rowB0 = blockIdx.x * 128;
  const int r0 = tid >> 2, kk = (tid & 3) << 3;
  const int bb = rowB0 >> 13;
  const int nB = rowB0 & 8191;
  bf16_t* vb = qkv + 2 * WH + (size_t)bb * (NTOK * CDIM);

  for (int jt = 0; jt < 9; jt++) {
    const int rowA0 = jt * 128;
    const int which = jt / 3;
    const int jtt = jt - which * 3;
    f32x4 acc[4][4];
#pragma unroll
    for (int i = 0; i < 4; i++)
#pragma unroll
      for (int j = 0; j < 4; j++) acc[i][j] = (f32x4){0.f, 0.f, 0.f, 0.f};

    for (int k0 = 0; k0 < CDIM; k0 += 32) {
      bf16x8 a0 = load8<BF16>(Wqkv, (rowA0 + r0) * CDIM + k0 + kk);
      bf16x8 a1 = load8<BF16>(Wqkv, (rowA0 + r0 + 64) * CDIM + k0 + kk);
      bf16x8 b0 = load8<BF16>(X, (rowB0 + r0) * CDIM + k0 + kk);
      bf16x8 b1 = load8<BF16>(X, (rowB0 + r0 + 64) * CDIM + k0 + kk);
      __syncthreads();
      *(bf16x8*)&As[tid * 8] = a0;
      *(bf16x8*)&As[(tid + 256) * 8] = a1;
      *(bf16x8*)&Bs[tid * 8] = b0;
      *(bf16x8*)&Bs[(tid + 256) * 8] = b1;
      __syncthreads();
      bf16x8 af[4], bfr[4];
#pragma unroll
      for (int i = 0; i < 4; i++) {
        af[i]  = *(const bf16x8*)&As[(wr * 64 + i * 16 + l16) * 32 + q4 * 8];
        bfr[i] = *(const bf16x8*)&Bs[(wc * 64 + i * 16 + l16) * 32 + q4 * 8];
      }
      if (which < 2) {
#pragma unroll
        for (int i = 0; i < 4; i++)
#pragma unroll
          for (int j = 0; j < 4; j++) acc[i][j] = mfma16(bfr[j], af[i], acc[i][j]);
      } else {
#pragma unroll
        for (int i = 0; i < 4; i++)
#pragma unroll
          for (int j = 0; j < 4; j++) acc[i][j] = mfma16(af[i], bfr[j], acc[i][j]);
      }
    }

    if (which < 2) {
#pragma unroll
      for (int i = 0; i < 4; i++) {
        const int rin = jtt * 128 + wr * 64 + i * 16 + l16;
        const int h = rin / 48, dh = rin - h * 48;
        bf16_t* plane = qkv + which * WH + (size_t)(bb * 8 + h) * DHN;
#pragma unroll
        for (int j = 0; j < 4; j++) {
          bf16x4 o = {(bf16_t)acc[i][j][0], (bf16_t)acc[i][j][1],
                      (bf16_t)acc[i][j][2], (bf16_t)acc[i][j][3]};
          store_qk4(plane, dh, nB + wc * 64 + j * 16 + q4 * 4, o);
        }
      }
    } else {
#pragma unroll
      for (int i = 0; i < 4; i++) {
        const int c0 = jtt * 128 + wr * 64 + i * 16 + q4 * 4;
#pragma unroll
        for (int j = 0; j < 4; j++) {
          bf16x4 o = {(bf16_t)acc[i][j][0], (bf16_t)acc[i][j][1],
                      (bf16_t)acc[i][j][2], (bf16_t)acc[i][j][3]};
          store_v4(vb, nB + wc * 64 + j * 16 + l16, c0, o);
        }
      }
    }
  }
}

__global__ __launch_bounds__(256, 2) void k_gemm_qkv_bf16(
    const void* __restrict__ X, const void* __restrict__ Wqkv,
    bf16_t* __restrict__ qkv, const int* __restrict__ flagp) {
  __shared__ __align__(16) bf16_t As[128 * 32];
  __shared__ __align__(16) bf16_t Bs[128 * 32];
  if (!*flagp) return;
  qkv_body_legacy<true>(X, Wqkv, qkv, As, Bs);
}

__global__ __launch_bounds__(256, 2) void k_gemm_qkv_f32(
    const void* __restrict__ X, const void* __restrict__ Wqkv,
    bf16_t* __restrict__ qkv, const int* __restrict__ flagp) {
  __shared__ __align__(16) bf16_t As[128 * 32];
  __shared__ __align__(16) bf16_t Bs[128 * 32];
  if (*flagp) return;
  qkv_body_legacy<false>(X, Wqkv, qkv, As, Bs);
}

// ---------------- K2: Gram S=Q K^T + sumsq (barrier-free frag GEMM) ----------------
// Grid (8 slices, 64 bh), 4 waves; wave wv covers 256 tokens = 8 chunks of 32.
// k-loop: frags direct from global (coalesced, streamed once), 9+6 MFMA/chunk
// (6 extra = Q.Q^T / K.K^T whose diagonals are the sumsq). 2 barriers total.
__global__ __launch_bounds__(256, 2) void k_gram(
    const bf16_t* __restrict__ qkv, float* __restrict__ S_acc, float* __restrict__ ssq_acc) {
  __shared__ __align__(16) float sm[9312];  // red 4x2304 + ssq 96
  float* ssq_sm = sm + 9216;

  const int tid = threadIdx.x;
  const int wv = tid >> 6, lane = tid & 63, q4 = lane >> 4, l16 = lane & 15;
  const int s = blockIdx.x, bh = blockIdx.y;
  const bf16_t* Qg = qkv + (size_t)bh * DHN;
  const bf16_t* Kg = qkv + WH + (size_t)bh * DHN;

  if (tid < 96) ssq_sm[tid] = 0.f;
  __syncthreads();

  f32x4 acc[3][3], accq[3], acck[3];
#pragma unroll
  for (int i = 0; i < 3; i++) {
    accq[i] = (f32x4){0.f, 0.f, 0.f, 0.f};
    acck[i] = (f32x4){0.f, 0.f, 0.f, 0.f};
#pragma unroll
    for (int j = 0; j < 3; j++) acc[i][j] = (f32x4){0.f, 0.f, 0.f, 0.f};
  }

  const int tt0 = s * 32 + wv * 8;  // first token-tile (32-token tiles)
#pragma unroll 2
  for (int kc = 0; kc < 8; kc++) {
    const int tt = tt0 + kc;
    bf16x8 qf[3], kf[3];
#pragma unroll
    for (int i = 0; i < 3; i++) {
      qf[i] = *(const bf16x8*)(Qg + (size_t)(i * 256 + tt) * 512 + lane * 8);
      kf[i] = *(const bf16x8*)(Kg + (size_t)(i * 256 + tt) * 512 + lane * 8);
    }
#pragma unroll
    for (int i = 0; i < 3; i++) {
      accq[i] = mfma16(qf[i], qf[i], accq[i]);
      acck[i] = mfma16(kf[i], kf[i], acck[i]);
#pragma unroll
      for (int j = 0; j < 3; j++) acc[i][j] = mfma16(qf[i], kf[j], acc[i][j]);
    }
  }

  // diag extraction: lane holds D[q4*4+r][l16]; diag where l16 == q4*4+r
#pragma unroll
  for (int r = 0; r < 4; r++) {
    if (l16 == q4 * 4 + r) {
#pragma unroll
      for (int i = 0; i < 3; i++) {
        atomicAdd(&ssq_sm[i * 16 + l16], accq[i][r]);
        atomicAdd(&ssq_sm[48 + i * 16 + l16], acck[i][r]);
      }
    }
  }

  // cross-wave S reduction
  float* red = sm;
#pragma unroll
  for (int i = 0; i < 3; i++)
#pragma unroll
    for (int j = 0; j < 3; j++)
#pragma unroll
      for (int r = 0; r < 4; r++)
        red[wv * 2304 + (i * 3 + j) * 256 + lane * 4 + r] = acc[i][j][r];
  __syncthreads();
  for (int idx = tid; idx < 2304; idx += 256) {
    const float v = red[idx] + red[2304 + idx] + red[4608 + idx] + red[6912 + idx];
    const int tile = idx >> 8, ln = (idx >> 2) & 63, r = idx & 3;
    const int i = tile / 3, j = tile - i * 3;
    const int d = i * 16 + ((ln >> 4) << 2) + r;
    const int e = j * 16 + (ln & 15);
    atomicAdd(&S_acc[bh * 2304 + d * 48 + e], v);
  }
  if (tid < 96) atomicAdd(&ssq_acc[bh * 96 + tid], ssq_sm[tid]);
}

// ---------------- K3: softmax(S / (|q_d||k_e|)) ----------------
__global__ void k_softmax(const float* __restrict__ S_acc, const float* __restrict__ ssq_acc,
                          float* __restrict__ attn_f) {
  __shared__ float invk_sm[48];
  const int bh = blockIdx.x, d = threadIdx.x;
  if (d < 48) invk_sm[d] = 1.f / fmaxf(sqrtf(ssq_acc[bh * 96 + 48 + d]), 1e-12f);
  __syncthreads();
  if (d < 48) {
    const float invq = 1.f / fmaxf(sqrtf(ssq_acc[bh * 96 + d]), 1e-12f);
    float lg[48], mx = -1e30f;
#pragma unroll
    for (int e = 0; e < 48; e++) {
      lg[e] = S_acc[bh * 2304 + d * 48 + e] * invq * invk_sm[e];
      mx = fmaxf(mx, lg[e]);
    }
    float ssum = 0.f;
#pragma unroll
    for (int e = 0; e < 48; e++) { lg[e] = expf(lg[e] - mx); ssum += lg[e]; }
    const float inv = 1.f / ssum;
#pragma unroll
    for (int e = 0; e < 48; e++) attn_f[bh * 2304 + d * 48 + e] = lg[e] * inv;
  }
}

// ---------------- K4: Weff (frag-tiled output) ----------------
__global__ void k_weff(
    const float* __restrict__ attn_f, const void* __restrict__ Wp,
    bf16_t* __restrict__ Weff, const int* __restrict__ flagp) {
  __shared__ float a_sm[2304];
  __shared__ float w_sm[2304];
  const int isb = *flagp;
  const int bid = blockIdx.x;
  const int ct = bid & 7, h = (bid >> 3) & 7, b = bid >> 6;
  const int bh = b * 8 + h;
  const int tid = threadIdx.x;

  for (int i = tid; i < 2304; i += 256) {
    a_sm[i] = attn_f[bh * 2304 + i];
    const int r = i / 48, c = i - r * 48;
    const int gi = (ct * 48 + r) * CDIM + h * 48 + c;
    w_sm[i] = isb ? (float)((const bf16_t*)Wp)[gi] : ((const float*)Wp)[gi];
  }
  __syncthreads();

  bf16_t* Wb = Weff + (size_t)b * 147456;
  for (int o = tid; o < 2304; o += 256) {
    const int r = o / 48, e = o - r * 48;
    float s = 0.f;
#pragma unroll 8
    for (int d = 0; d < 48; d++) s += w_sm[r * 48 + d] * a_sm[d * 48 + e];
    const int cp = ct * 48 + r;          // c' row
    const int cc = h * 48 + e;           // c col (k-dim)
    const int t = (cp >> 4) * 12 + (cc >> 5);
    const int w = (cp & 15) | (((cc >> 3) & 3) << 4);
    Wb[t * 512 + w * 8 + (cc & 7)] = (bf16_t)s;
  }
}

// ---------------- K5: out = Weff_b @ V_b^T + bias (barrier-free frag GEMM) ----
// Grid (1024): block = 64 tokens. V-slice (48KB frag-contig) staged once;
// Weff_b (288KB frag, L2-resident) read as global frags. ct loop 3x128 c'.
__global__ __launch_bounds__(256, 3) void k_gemm_out(
    const bf16_t* __restrict__ Weff, const bf16_t* __restrict__ qkv,
    const void* __restrict__ bias, void* __restrict__ out, const int* __restrict__ flagp) {
  __shared__ __align__(16) bf16_t Bs[24576];  // 48 tiles * 512

  const int isb = *flagp;
  const int tid = threadIdx.x;
  const int lane = tid & 63;
  const int wv = tid >> 6;
  const int q4 = lane >> 4, l16 = lane & 15;
  const int tok0 = blockIdx.x * 64;
  const int bb = tok0 >> 13;
  const int nB = tok0 & 8191;

  const bf16_t* Vb = qkv + 2 * WH + (size_t)bb * (NTOK * CDIM);
  const bf16_t* Af = Weff + (size_t)bb * 147456;

  const bf16_t* Bsrc = Vb + (size_t)nB * CDIM;  // (nB>>4)*12*512 == nB*384
#pragma unroll
  for (int s = 0; s < 12; s++) {
    const int chunk = s * 256 + tid;
    gload16(Bs + chunk * 8, Bsrc + chunk * 8);
  }
  __syncthreads();

  for (int ct = 0; ct < 3; ct++) {
    f32x4 acc[2][4];
#pragma unroll
    for (int i = 0; i < 2; i++)
#pragma unroll
      for (int j = 0; j < 4; j++) acc[i][j] = (f32x4){0.f, 0.f, 0.f, 0.f};

    const int rt0 = ct * 8 + wv * 2;
#pragma unroll 2
    for (int kc = 0; kc < 12; kc++) {
      bf16x8 af[2], bfr[4];
#pragma unroll
      for (int i = 0; i < 2; i++)
        af[i] = *(const bf16x8*)(Af + (size_t)((rt0 + i) * 12 + kc) * 512 + lane * 8);
#pragma unroll
      for (int j = 0; j < 4; j++)
        bfr[j] = *(const bf16x8*)&Bs[(j * 12 + kc) * 512 + lane * 8];
#pragma unroll
      for (int i = 0; i < 2; i++)
#pragma unroll
        for (int j = 0; j < 4; j++) acc[i][j] = mfma16(af[i], bfr[j], acc[i][j]);
    }

    // acc[i][j][r] = D[c' = ct*128 + wv*32 + i*16 + q4*4 + r][tok = tok0 + j*16 + l16]
#pragma unroll
    for (int i = 0; i < 2; i++) {
      const int cg = ct * 128 + wv * 32 + i * 16 + q4 * 4;
      float bv[4];
#pragma unroll
      for (int r = 0; r < 4; r++)
        bv[r] = isb ? (float)((const bf16_t*)bias)[cg + r] : ((const float*)bias)[cg + r];
#pragma unroll
      for (int j = 0; j < 4; j++) {
        const int tokg = tok0 + j * 16 + l16;
        const int oi = tokg * CDIM + cg;
        if (isb) {
          bf16x4 o = {(bf16_t)(acc[i][j][0] + bv[0]), (bf16_t)(acc[i][j][1] + bv[1]),
                      (bf16_t)(acc[i][j][2] + bv[2]), (bf16_t)(acc[i][j][3] + bv[3])};
          *(bf16x4*)((bf16_t*)out + oi) = o;
        } else {
          f32x4 o = {acc[i][j][0] + bv[0], acc[i][j][1] + bv[1],
                     acc[i][j][2] + bv[2], acc[i][j][3] + bv[3]};
          *(f32x4*)((float*)out + oi) = o;
        }
      }
    }
  }
}

extern "C" void kernel_launch(void* const* d_in, const int* in_sizes, int n_in,
                              void* d_out, int out_size, void* d_ws, size_t ws_size,
                              hipStream_t stream) {
  (void)in_sizes; (void)n_in; (void)out_size;
  const void* X    = d_in[0];
  const void* Wqkv = d_in[1];
  const void* Wp   = d_in[2];
  const void* bias = d_in[3];

  char* ws = (char*)d_ws;
  bf16_t* qkv    = (bf16_t*)ws;                     // 3*WH bf16 = 150,994,944 B
  float*  S_acc  = (float*)(ws + 150994944);        // 64*2304 f32
  float*  ssq    = (float*)(ws + 151584768);        // 64*96 f32
  float*  attn_f = (float*)(ws + 151609344);        // 64*2304 f32
  bf16_t* Weff   = (bf16_t*)(ws + 152199168);       // 8*384*384 bf16 (frag)
  int*    flag   = (int*)(ws + 154558464);
  bf16_t* Xf     = (bf16_t*)(ws + 154558720);       // 50,331,648 B (frag)
  bf16_t* Wf     = (bf16_t*)(ws + 204890368);       // 884,736 B -> end 205,775,104

  const bool have_cvt_ws = ws_size >= 205775104ULL;

  k_probe<<<dim3(1), 256, 0, stream>>>((const uint32_t*)X, flag);
  k_zero<<<dim3(600), 256, 0, stream>>>(S_acc, 153600);
  if (have_cvt_ws) {
    k_cvt<<<dim3(2048), 256, 0, stream>>>(X, Wqkv, Xf, Wf, flag);
    k_gemm_qkv<<<dim3(1024), 256, 0, stream>>>(Xf, Wf, qkv);
  } else {
    k_gemm_qkv_bf16<<<dim3(512), 256, 0, stream>>>(X, Wqkv, qkv, flag);
    k_gemm_qkv_f32<<<dim3(512), 256, 0, stream>>>(X, Wqkv, qkv, flag);
  }
  k_gram<<<dim3(8, 64), 256, 0, stream>>>(qkv, S_acc, ssq);
  k_softmax<<<dim3(64), 64, 0, stream>>>(S_acc, ssq, attn_f);
  k_weff<<<dim3(512), 256, 0, stream>>>(attn_f, Wp, Weff, flag);
  k_gemm_out<<<dim3(1024), 256, 0, stream>>>(Weff, qkv, bias, d_out, flag);
}